// Round 1
// baseline (694.677 us; speedup 1.0000x reference)
//
#include <hip/hip_runtime.h>

#define CCH 64

// ---------------- CSR construction ----------------

__global__ void hist_kernel(const int* __restrict__ dst, int* __restrict__ cnt, int E) {
    int e = blockIdx.x * blockDim.x + threadIdx.x;
    if (e < E) atomicAdd(&cnt[dst[e]], 1);
}

__global__ void dinv_kernel(const int* __restrict__ cnt, float* __restrict__ dinv, int N) {
    int i = blockIdx.x * blockDim.x + threadIdx.x;
    // degree includes the self-loop (+1), so always > 0
    if (i < N) dinv[i] = rsqrtf((float)cnt[i] + 1.0f);
}

// Two-level exclusive scan over cnt[N] -> row_ptr (1024 elems / block)
__global__ void scan1(const int* __restrict__ cnt, int* __restrict__ part,
                      int* __restrict__ bsum, int N) {
    __shared__ int s[256];
    int t = threadIdx.x;
    int base = blockIdx.x * 1024 + t * 4;
    int v0 = (base + 0 < N) ? cnt[base + 0] : 0;
    int v1 = (base + 1 < N) ? cnt[base + 1] : 0;
    int v2 = (base + 2 < N) ? cnt[base + 2] : 0;
    int v3 = (base + 3 < N) ? cnt[base + 3] : 0;
    s[t] = v0 + v1 + v2 + v3;
    __syncthreads();
    for (int off = 1; off < 256; off <<= 1) {
        int xx = (t >= off) ? s[t - off] : 0;
        __syncthreads();
        s[t] += xx;
        __syncthreads();
    }
    int excl = (t == 0) ? 0 : s[t - 1];
    if (t == 255) bsum[blockIdx.x] = s[255];
    if (base + 0 < N) part[base + 0] = excl;
    if (base + 1 < N) part[base + 1] = excl + v0;
    if (base + 2 < N) part[base + 2] = excl + v0 + v1;
    if (base + 3 < N) part[base + 3] = excl + v0 + v1 + v2;
}

__global__ void scan2(int* __restrict__ bsum, int NB) {
    __shared__ int s[256];
    int t = threadIdx.x;
    int base = t * 4;
    int v0 = (base + 0 < NB) ? bsum[base + 0] : 0;
    int v1 = (base + 1 < NB) ? bsum[base + 1] : 0;
    int v2 = (base + 2 < NB) ? bsum[base + 2] : 0;
    int v3 = (base + 3 < NB) ? bsum[base + 3] : 0;
    s[t] = v0 + v1 + v2 + v3;
    __syncthreads();
    for (int off = 1; off < 256; off <<= 1) {
        int xx = (t >= off) ? s[t - off] : 0;
        __syncthreads();
        s[t] += xx;
        __syncthreads();
    }
    int excl = (t == 0) ? 0 : s[t - 1];
    if (base + 0 < NB) bsum[base + 0] = excl;
    if (base + 1 < NB) bsum[base + 1] = excl + v0;
    if (base + 2 < NB) bsum[base + 2] = excl + v0 + v1;
    if (base + 3 < NB) bsum[base + 3] = excl + v0 + v1 + v2;
}

__global__ void scan3(int* __restrict__ row_ptr, const int* __restrict__ bsum,
                      int* __restrict__ cursor, int N, int E) {
    int i = blockIdx.x * blockDim.x + threadIdx.x;
    if (i < N) {
        int v = row_ptr[i] + bsum[i >> 10];
        row_ptr[i] = v;
        cursor[i] = v;
    }
    if (i == 0) row_ptr[N] = E;
}

__global__ void fill_kernel(const int* __restrict__ src, const int* __restrict__ dst,
                            const float* __restrict__ dinv, int* __restrict__ cursor,
                            int* __restrict__ col, float* __restrict__ val, int E) {
    int e = blockIdx.x * blockDim.x + threadIdx.x;
    if (e < E) {
        int s = src[e], d = dst[e];
        int pos = atomicAdd(&cursor[d], 1);
        col[pos] = s;
        val[pos] = dinv[s] * dinv[d];
    }
}

// ---------------- propagation: one wave per node, lane = channel ----------------

__global__ void prop_kernel(const float* __restrict__ hin, float* __restrict__ hout,
                            const int* __restrict__ row_ptr, const int* __restrict__ col,
                            const float* __restrict__ val, const float* __restrict__ dinv,
                            int N) {
    int node = (blockIdx.x * blockDim.x + threadIdx.x) >> 6;
    int lane = threadIdx.x & 63;
    if (node >= N) return;
    int beg = row_ptr[node];
    int end = row_ptr[node + 1];
    float di = dinv[node];
    float acc = di * di * hin[(size_t)node * CCH + lane];  // analytic self-loop
    for (int e = beg; e < end; ++e) {
        int j = col[e];        // wave-uniform broadcast load
        float w = val[e];      // wave-uniform broadcast load
        acc = fmaf(w, hin[(size_t)j * CCH + lane], acc);  // coalesced 256B row gather
    }
    hout[(size_t)node * CCH + lane] = acc;
}

// ---------------- final: out = 2x + h @ W^T + b - x_pre ----------------

__global__ void final_kernel(const float* __restrict__ h, const float* __restrict__ x,
                             const float* __restrict__ xp, const float* __restrict__ W,
                             const float* __restrict__ b, float* __restrict__ out, int N) {
    __shared__ float Wt[CCH * 65];  // Wt[k][c] = W[c][k], stride 65 to kill bank conflicts
    for (int i = threadIdx.x; i < CCH * CCH; i += blockDim.x) {
        int c = i >> 6, k = i & 63;
        Wt[k * 65 + c] = W[i];  // W row-major [c][k], i = c*64+k
    }
    __syncthreads();
    int node = (blockIdx.x * blockDim.x + threadIdx.x) >> 6;
    int lane = threadIdx.x & 63;
    if (node >= N) return;
    size_t base = (size_t)node * CCH + lane;
    float hv = h[base];     // read own row element BEFORE any write (h may alias out)
    float acc = b[lane];
    #pragma unroll
    for (int k = 0; k < CCH; ++k) {
        float hk = __shfl(hv, k, 64);
        acc = fmaf(hk, Wt[k * 65 + lane], acc);
    }
    out[base] = fmaf(2.0f, x[base], acc) - xp[base];
}

extern "C" void kernel_launch(void* const* d_in, const int* in_sizes, int n_in,
                              void* d_out, int out_size, void* d_ws, size_t ws_size,
                              hipStream_t stream) {
    const float* x    = (const float*)d_in[0];
    const float* xpre = (const float*)d_in[1];
    const int*   ei   = (const int*)d_in[2];
    const float* W    = (const float*)d_in[3];
    const float* b    = (const float*)d_in[4];
    float* out = (float*)d_out;

    const int N = in_sizes[0] / CCH;
    const int E = in_sizes[2] / 2;
    const int* src = ei;
    const int* dst = ei + E;

    // workspace partition (256B aligned)
    char* p = (char*)d_ws;
    auto alloc = [&](size_t bytes) -> char* {
        char* r = p;
        p += (bytes + 255) & ~(size_t)255;
        return r;
    };
    int*   cnt     = (int*)alloc((size_t)N * 4);
    int*   row_ptr = (int*)alloc(((size_t)N + 1) * 4);
    int*   cursor  = (int*)alloc((size_t)N * 4);
    float* dinv    = (float*)alloc((size_t)N * 4);
    int*   col     = (int*)alloc((size_t)E * 4);
    float* val     = (float*)alloc((size_t)E * 4);
    float* h0      = (float*)alloc((size_t)N * CCH * 4);
    const int NB   = (N + 1023) / 1024;
    int*   bsum    = (int*)alloc((size_t)NB * 4);
    float* h1      = out;  // reuse output buffer as second ping-pong buffer

    hipMemsetAsync(cnt, 0, (size_t)N * 4, stream);
    hist_kernel<<<(E + 255) / 256, 256, 0, stream>>>(dst, cnt, E);
    dinv_kernel<<<(N + 255) / 256, 256, 0, stream>>>(cnt, dinv, N);
    scan1<<<NB, 256, 0, stream>>>(cnt, row_ptr, bsum, N);
    scan2<<<1, 256, 0, stream>>>(bsum, NB);
    scan3<<<(N + 255) / 256, 256, 0, stream>>>(row_ptr, bsum, cursor, N, E);
    fill_kernel<<<(E + 255) / 256, 256, 0, stream>>>(src, dst, dinv, cursor, col, val, E);

    const int pgrid = (N + 3) / 4;  // 4 waves (nodes) per 256-thread block
    prop_kernel<<<pgrid, 256, 0, stream>>>(x,  h0, row_ptr, col, val, dinv, N);  // hop 1
    prop_kernel<<<pgrid, 256, 0, stream>>>(h0, h1, row_ptr, col, val, dinv, N);  // hop 2
    prop_kernel<<<pgrid, 256, 0, stream>>>(h1, h0, row_ptr, col, val, dinv, N);  // hop 3
    prop_kernel<<<pgrid, 256, 0, stream>>>(h0, h1, row_ptr, col, val, dinv, N);  // hop 4

    final_kernel<<<pgrid, 256, 0, stream>>>(h1, x, xpre, W, b, out, N);
}